// Round 1
// baseline (585.058 us; speedup 1.0000x reference)
//
#include <hip/hip_runtime.h>
#include <math.h>

#define BB 64
#define TT 1024
#define KK 128
#define START_TAG 126
#define STOP_TAG 127
#define NTHREADS 512   // 8 waves; thread t: j = t&127 (row), q = t>>7 (k-chunk of 32)

// Forward algorithm in normalized exp-domain:
//   E[j][k] = exp(T[j][k] - maxT[j])   (precomputed, registers: 32 per thread)
//   e[k]    = exp(alpha[k] - M)        (LDS, 128 floats)
//   dot_j   = sum_k e[k]*E[j][k]       (FP32 matvec, the per-step kernel of work)
//   new[j]  = feat[t][j] + M + maxT[j] + log(dot_j)
//   row START of T is all NEG => E[START][k]=1 => dot_START = sum_k e[k],
//   giving the running-normalizer update M += log(sum e) for free (no max reduce).
__global__ __launch_bounds__(NTHREADS) void crf_forward(
    const float* __restrict__ feats,   // [B,T,K]
    const int*   __restrict__ tags,    // [B,T]
    const int*   __restrict__ lens,    // [B]
    const float* __restrict__ trans,   // [K,K]
    float*       __restrict__ out_pb)  // [B]: forward_score - gold_score
{
  __shared__ float Tld[KK][KK + 1];                 // raw transitions (padded) — also reused by gold score
  __shared__ __align__(16) float e_lds[KK];         // exp-normalized alpha
  __shared__ float partial[NTHREADS];
  __shared__ float wsum[NTHREADS / 64];

  const int tid = threadIdx.x;
  const int b   = blockIdx.x;
  const int j   = tid & (KK - 1);
  const int q   = tid >> 7;                         // 0..3, k in [32q, 32q+32)
  const int L   = lens[b];
  const float* fb = feats + (size_t)b * TT * KK;

  // ---- stage transitions into LDS (coalesced global read) ----
  for (int i = tid; i < KK * KK; i += NTHREADS)
    Tld[i >> 7][i & (KK - 1)] = trans[i];
  __syncthreads();

  // ---- per-thread E row-chunk into registers; row max via LDS exchange ----
  float mT = -INFINITY;
  #pragma unroll
  for (int i = 0; i < 32; ++i) mT = fmaxf(mT, Tld[j][q * 32 + i]);
  partial[tid] = mT;
  __syncthreads();
  const float maxTj = fmaxf(fmaxf(partial[j], partial[j + 128]),
                            fmaxf(partial[j + 256], partial[j + 384]));
  float Er[32];
  #pragma unroll
  for (int i = 0; i < 32; ++i) Er[i] = __expf(Tld[j][q * 32 + i] - maxTj);
  __syncthreads();  // partial[] about to be reused

  // epilogue lanes (wave 0) cache maxT for their two rows
  // lane l handles rows l and l+64; row maxes come from partial[] trick:
  // recompute via LDS once: store per-j maxT
  if (q == 0) partial[j] = maxTj;                   // partial[0..127] = maxT[j]
  __syncthreads();
  float mT0 = 0.f, mT1 = 0.f;
  if (tid < 64) { mT0 = partial[tid]; mT1 = partial[tid + 64]; }
  __syncthreads();

  // ---- init t=0: alpha = NEG except alpha[START] = feats[b,0,START] ----
  if (tid < KK) e_lds[tid] = (tid == START_TAG) ? 1.0f : 0.0f;
  float M = 0.f;
  if (tid < 64) M = fb[START_TAG];
  float f0 = 0.f, f1 = 0.f;
  if (tid < 64 && L > 1) { f0 = fb[KK + tid]; f1 = fb[KK + tid + 64]; }
  __syncthreads();

  // ---- main recurrence: L-1 steps ----
  for (int t = 1; t < L; ++t) {
    // dot phase (all 512 threads): 32 FMAs each, e broadcast-read as float4
    float s0 = 0.f, s1 = 0.f, s2 = 0.f, s3 = 0.f;
    const float4* e4 = (const float4*)(e_lds + q * 32);
    #pragma unroll
    for (int i = 0; i < 8; ++i) {
      float4 ev = e4[i];
      s0 = fmaf(ev.x, Er[4 * i + 0], s0);
      s1 = fmaf(ev.y, Er[4 * i + 1], s1);
      s2 = fmaf(ev.z, Er[4 * i + 2], s2);
      s3 = fmaf(ev.w, Er[4 * i + 3], s3);
    }
    partial[tid] = (s0 + s1) + (s2 + s3);
    __syncthreads();

    // epilogue (wave 0 only): lanes 0..63 handle rows (lane, lane+64)
    if (tid < 64) {
      float d0 = (partial[tid]      + partial[tid + 128]) +
                 (partial[tid + 256] + partial[tid + 384]);
      float d1 = (partial[tid + 64]  + partial[tid + 192]) +
                 (partial[tid + 320] + partial[tid + 448]);
      float ld0 = __logf(d0);
      float ld1 = __logf(d1);
      // row 126 (=START) dot = sum_k e[k]; its log lives in ld1 of lane 62
      float delta = __shfl(ld1, 62, 64);            // = log(sum e)
      float u0 = f0 + mT0 + ld0;                    // new[j]   - M
      float u1 = f1 + mT1 + ld1;                    // new[j+64]- M
      e_lds[tid]      = __expf(u0 - delta);
      e_lds[tid + 64] = __expf(u1 - delta);
      M += delta;
      if (t + 1 < L) {                              // prefetch next feat row
        f0 = fb[(size_t)(t + 1) * KK + tid];
        f1 = fb[(size_t)(t + 1) * KK + tid + 64];
      }
    }
    __syncthreads();
  }

  // ---- terminal: forward = M + log(sum_k e[k]) ; computed by wave 0 ----
  float fwd = 0.f;
  if (tid < 64) {
    float s = e_lds[tid] + e_lds[tid + 64];
    #pragma unroll
    for (int m = 1; m < 64; m <<= 1) s += __shfl_xor(s, m, 64);
    fwd = M + __logf(s);                            // all lanes of wave 0 hold fwd
  }

  // ---- gold score (all threads; Tld still holds raw transitions) ----
  float g = 0.f;
  const int* tg = tags + b * TT;
  for (int t = tid; t < TT; t += NTHREADS) {
    if (t < L)     g += fb[(size_t)t * KK + tg[t]];
    if (t < L - 1) g += Tld[tg[t + 1]][tg[t]];
  }
  #pragma unroll
  for (int m = 1; m < 64; m <<= 1) g += __shfl_xor(g, m, 64);
  if ((tid & 63) == 0) wsum[tid >> 6] = g;
  __syncthreads();
  if (tid == 0) {
    float gold = 0.f;
    #pragma unroll
    for (int w = 0; w < NTHREADS / 64; ++w) gold += wsum[w];
    out_pb[b] = fwd - gold;
  }
}

__global__ void crf_mean(const float* __restrict__ pb, float* __restrict__ out) {
  int tid = threadIdx.x;  // 64 threads, one wave
  float v = pb[tid];
  #pragma unroll
  for (int m = 1; m < 64; m <<= 1) v += __shfl_xor(v, m, 64);
  if (tid == 0) out[0] = v * (1.0f / 64.0f);
}

extern "C" void kernel_launch(void* const* d_in, const int* in_sizes, int n_in,
                              void* d_out, int out_size, void* d_ws, size_t ws_size,
                              hipStream_t stream) {
  const float* feats = (const float*)d_in[0];
  const int*   tags  = (const int*)d_in[1];
  const int*   lens  = (const int*)d_in[2];
  const float* trans = (const float*)d_in[3];
  float* pb = (float*)d_ws;   // 64 floats of scratch
  crf_forward<<<BB, NTHREADS, 0, stream>>>(feats, tags, lens, trans, pb);
  crf_mean<<<1, 64, 0, stream>>>(pb, (float*)d_out);
}

// Round 2
// 450.282 us; speedup vs baseline: 1.2993x; 1.2993x over previous
//
#include <hip/hip_runtime.h>
#include <math.h>

#define BB 64
#define TT 1024
#define KK 128
#define START_TAG 126
#define STOP_TAG 127
#define NTHREADS 512   // 8 waves; thread t: j = t&127 (row), q = t>>7 (k-chunk of 32)
#define CS 64          // timesteps of F staged per chunk (32 KB LDS)

typedef float v2f __attribute__((ext_vector_type(2)));

// Forward algorithm, log/exp-free inner chain:
//   E[j][k] = exp(T[j][k] - maxT[j])      (registers, float2 pairs for pk_fma)
//   F[t][j] = exp(feat[t][j] + maxT[j])   (precomputed per 64-step chunk, off-chain)
//   d_j     = sum_k e_k E[j][k]           (pk_fma matvec; d_START = sum_k e_k = s, free)
//   e'_j    = d_j * F[t][j] * (1/s)       (pure mul chain)
//   M      += log(s)                      (wave 0 only; consumed only at the end)
// Feats staged to LDS in 64-step chunks via register prefetch, so the barrier's
// vmcnt(0) drain eats HBM latency once per 64 steps instead of every step.
__global__ __launch_bounds__(NTHREADS) void crf_forward(
    const float* __restrict__ feats,   // [B,T,K]
    const int*   __restrict__ tags,    // [B,T]
    const int*   __restrict__ lens,    // [B]
    const float* __restrict__ trans,   // [K,K]
    float*       __restrict__ out_pb)  // [B]: forward_score - gold_score
{
  __shared__ float Tld[KK][KK + 1];                 // raw transitions; reused by gold score
  __shared__ __align__(16) float e_lds[KK];
  __shared__ float partial[NTHREADS];
  __shared__ float maxT_lds[KK];
  __shared__ __align__(16) float Fbuf[CS * KK];     // 32 KB: F for current chunk
  __shared__ float wsum[NTHREADS / 64];

  const int tid = threadIdx.x;
  const int b   = blockIdx.x;
  const int j   = tid & (KK - 1);
  const int q   = tid >> 7;                         // 0..3
  const int L   = lens[b];
  const float* fb = feats + (size_t)b * TT * KK;

  // ---- stage transitions into LDS ----
  for (int i = tid; i < KK * KK; i += NTHREADS)
    Tld[i >> 7][i & (KK - 1)] = trans[i];
  __syncthreads();

  // ---- per-thread E row-chunk (as float2 pairs); row max via LDS exchange ----
  float mT = -INFINITY;
  #pragma unroll
  for (int i = 0; i < 32; ++i) mT = fmaxf(mT, Tld[j][q * 32 + i]);
  partial[tid] = mT;
  __syncthreads();
  const float maxTj = fmaxf(fmaxf(partial[j], partial[j + 128]),
                            fmaxf(partial[j + 256], partial[j + 384]));
  v2f Er2[16];
  #pragma unroll
  for (int i = 0; i < 16; ++i) {
    Er2[i][0] = __expf(Tld[j][q * 32 + 2 * i]     - maxTj);
    Er2[i][1] = __expf(Tld[j][q * 32 + 2 * i + 1] - maxTj);
  }
  __syncthreads();                                  // partial[] about to be reused
  if (q == 0) maxT_lds[j] = maxTj;

  // ---- init: e0 = onehot(START), M0 = feats[b,0,START] ----
  if (tid < KK) e_lds[tid] = (tid == START_TAG) ? 1.0f : 0.0f;
  float M = fb[START_TAG];                          // redundant across threads; wave 0's is used
  __syncthreads();                                  // maxT_lds + e_lds visible

  // per-thread 16-float maxT slice for F conversion (loop-invariant)
  const int j0 = (tid * 16) & (KK - 1);             // 16-aligned
  float4 mTv[4];
  #pragma unroll
  for (int i = 0; i < 4; ++i) mTv[i] = ((const float4*)maxT_lds)[(j0 >> 2) + i];

  // ---- prefetch chunk 0 feats into registers (16 floats/thread) ----
  float4 pf[4];
  {
    const float4* src = (const float4*)fb;
    #pragma unroll
    for (int i = 0; i < 4; ++i) pf[i] = src[tid * 4 + i];
  }

  // ---- chunked main recurrence ----
  for (int c = 0; c * CS < L; ++c) {
    // convert prefetched feats -> F = exp(feat + maxT), write to Fbuf
    float4* Fb4 = (float4*)Fbuf;
    #pragma unroll
    for (int i = 0; i < 4; ++i) {
      float4 v = pf[i];
      float4 m = mTv[i];
      float4 o;
      o.x = __expf(v.x + m.x); o.y = __expf(v.y + m.y);
      o.z = __expf(v.z + m.z); o.w = __expf(v.w + m.w);
      Fb4[tid * 4 + i] = o;
    }
    // issue prefetch for chunk c+1 (latency hidden across the next 64 steps)
    if ((c + 1) * CS < TT) {
      const float4* src = (const float4*)(fb + (size_t)(c + 1) * CS * KK);
      #pragma unroll
      for (int i = 0; i < 4; ++i) pf[i] = src[tid * 4 + i];
    }
    __syncthreads();                                // Fbuf visible

    const int t_begin = (c == 0) ? 1 : c * CS;
    const int t_end   = (L < (c + 1) * CS) ? L : (c + 1) * CS;
    for (int t = t_begin; t < t_end; ++t) {
      // dot phase: 16 pk_fma per thread, e broadcast-read from LDS
      const v2f* e2 = (const v2f*)(e_lds + q * 32);
      v2f a0 = {0.f, 0.f}, a1 = {0.f, 0.f}, a2 = {0.f, 0.f}, a3 = {0.f, 0.f};
      #pragma unroll
      for (int i = 0; i < 4; ++i) {
        a0 += e2[4 * i + 0] * Er2[4 * i + 0];
        a1 += e2[4 * i + 1] * Er2[4 * i + 1];
        a2 += e2[4 * i + 2] * Er2[4 * i + 2];
        a3 += e2[4 * i + 3] * Er2[4 * i + 3];
      }
      v2f asum = (a0 + a1) + (a2 + a3);
      float F = Fbuf[(t & (CS - 1)) * KK + j];      // off-chain, before barrier
      partial[tid] = asum[0] + asum[1];
      __syncthreads();

      // epilogue: waves 0-1 only (q==0 plus wave 0 for M); others go to barrier
      if (q == 0) {
        float d = (partial[j]       + partial[j + 128]) +
                  (partial[j + 256] + partial[j + 384]);
        float s = (partial[START_TAG]       + partial[START_TAG + 128]) +
                  (partial[START_TAG + 256] + partial[START_TAG + 384]);
        float r;
        asm("v_rcp_f32 %0, %1" : "=v"(r) : "v"(s));
        e_lds[j] = d * F * r;
        if (tid < 64) M += __logf(s);               // off the data chain
      }
      __syncthreads();
    }
  }

  // ---- terminal: fwd = M + log(sum_k e_k), wave 0 ----
  float fwd = 0.f;
  if (tid < 64) {
    float sm = e_lds[tid] + e_lds[tid + 64];
    #pragma unroll
    for (int m = 1; m < 64; m <<= 1) sm += __shfl_xor(sm, m, 64);
    fwd = M + __logf(sm);
  }

  // ---- gold score (all threads; Tld still holds raw transitions) ----
  float g = 0.f;
  const int* tg = tags + b * TT;
  for (int t = tid; t < TT; t += NTHREADS) {
    if (t < L)     g += fb[(size_t)t * KK + tg[t]];
    if (t < L - 1) g += Tld[tg[t + 1]][tg[t]];
  }
  #pragma unroll
  for (int m = 1; m < 64; m <<= 1) g += __shfl_xor(g, m, 64);
  if ((tid & 63) == 0) wsum[tid >> 6] = g;
  __syncthreads();
  if (tid == 0) {
    float gold = 0.f;
    #pragma unroll
    for (int w = 0; w < NTHREADS / 64; ++w) gold += wsum[w];
    out_pb[b] = fwd - gold;
  }
}

__global__ void crf_mean(const float* __restrict__ pb, float* __restrict__ out) {
  int tid = threadIdx.x;  // 64 threads, one wave
  float v = pb[tid];
  #pragma unroll
  for (int m = 1; m < 64; m <<= 1) v += __shfl_xor(v, m, 64);
  if (tid == 0) out[0] = v * (1.0f / 64.0f);
}

extern "C" void kernel_launch(void* const* d_in, const int* in_sizes, int n_in,
                              void* d_out, int out_size, void* d_ws, size_t ws_size,
                              hipStream_t stream) {
  const float* feats = (const float*)d_in[0];
  const int*   tags  = (const int*)d_in[1];
  const int*   lens  = (const int*)d_in[2];
  const float* trans = (const float*)d_in[3];
  float* pb = (float*)d_ws;   // 64 floats of scratch
  crf_forward<<<BB, NTHREADS, 0, stream>>>(feats, tags, lens, trans, pb);
  crf_mean<<<1, 64, 0, stream>>>(pb, (float*)d_out);
}